// Round 7
// baseline (790.636 us; speedup 1.0000x reference)
//
#include <hip/hip_runtime.h>
#include <stdint.h>

#define N_ 4096
#define D_ 512
#define H_ 8
#define E_ 131072
#define TD_ 1536
#define FD_ 2048

typedef unsigned short u16;
typedef __bf16 bf16x8 __attribute__((ext_vector_type(8)));
typedef u16 u16x8 __attribute__((ext_vector_type(8)));
typedef u16 u16x4 __attribute__((ext_vector_type(4)));
typedef float f32x4 __attribute__((ext_vector_type(4)));

__device__ __forceinline__ u16 f2bf(float f) {
  union { float f; uint32_t u; } v; v.f = f;
  return (u16)((v.u + 0x7FFFu + ((v.u >> 16) & 1u)) >> 16);
}
__device__ __forceinline__ float bf2f(u16 b) {
  union { uint32_t u; float f; } v; v.u = ((uint32_t)b) << 16; return v.f;
}

__device__ __forceinline__ void gload16(const u16* g, u16* l) {
  __builtin_amdgcn_global_load_lds(
      (const __attribute__((address_space(1))) void*)(uintptr_t)g,
      (__attribute__((address_space(3))) void*)(uint32_t)(uintptr_t)l, 16, 0, 0);
}

__device__ __forceinline__ f32x4 mfma16(bf16x8 a, bf16x8 b, f32x4 c) {
  return __builtin_amdgcn_mfma_f32_16x16x32_bf16(a, b, c, 0, 0, 0);
}

// ---------------- GEMM: C[M,N] = A[M,K] @ B[N,K]^T (+bias) -----------------
// MODE: 0 f32 store, 1 bf16 store, 3 exact-GELU bf16,
//       4 f32 store of (v + rowm[row*ldc+col])  (residual),
//       7 bf16 store of (v + deg*(ghp_part2 + msg_b)) / max(deg,1)  (aggr)
// AMODE: 0 A bf16 via global_load_lds (source-swizzled); 2 A f32 cast->bf16
template <int BM, int BN, int BK, int WM, int WN, int FM, int FN, int MODE, bool BIAS,
          int AMODE>
__global__ __launch_bounds__(WM * WN * 64) void gemm_bt(
    const u16* __restrict__ A, int lda, const u16* __restrict__ B, int ldb,
    void* __restrict__ Cout, int ldc, const float* __restrict__ bias,
    float scale, int Kchunk,
    const float* __restrict__ rowm, const float* __restrict__ rowinv,
    const int* __restrict__ auxI)
{
  static_assert(BM == WM * FM * 16 && BN == WN * FN * 16, "tile shape");
  static_assert(BK == 64, "LDS swizzle assumes BK=64");
  __shared__ alignas(16) u16 As[BM * BK];
  __shared__ alignas(16) u16 Bs[BN * BK];
  constexpr int NT = WM * WN * 64;
  const int tid = threadIdx.x;
  const int lane = tid & 63;
  const int wave = tid >> 6;
  const long tm = (long)blockIdx.x * BM;
  const long tn = (long)blockIdx.y * BN;
  const long k0 = (long)blockIdx.z * Kchunk;
  const int wm0 = (wave / WN) * (FM * 16);
  const int wn0 = (wave % WN) * (FN * 16);

  f32x4 acc[FM][FN] = {};

  constexpr int A_LOADS = (BM * BK) / (NT * 8);
  constexpr int B_LOADS = (BN * BK) / (NT * 8);

  for (int kt = 0; kt < Kchunk; kt += BK) {
    const long kb = k0 + kt;
#pragma unroll
    for (int i = 0; i < A_LOADS; ++i) {
      if constexpr (AMODE == 0) {
        int sB = (i * NT + wave * 64) * 8;
        int s = sB + lane * 8;
        int row = s / BK;
        int blk = (s % BK) >> 3;
        gload16(A + (tm + row) * (long)lda + kb + ((blk ^ (row & 7)) << 3), As + sB);
      } else {
        int s = (i * NT + tid) * 8;
        int row = s / BK, kk = s % BK;
        const float* Af = (const float*)A;
        f32x4 lo = *(const f32x4*)(Af + (tm + row) * (long)lda + kb + kk);
        f32x4 hi = *(const f32x4*)(Af + (tm + row) * (long)lda + kb + kk + 4);
        u16x8 w;
#pragma unroll
        for (int k = 0; k < 4; ++k) { w[k] = f2bf(lo[k]); w[4 + k] = f2bf(hi[k]); }
        *(u16x8*)(&As[row * BK + (kk ^ ((row & 7) << 3))]) = w;
      }
    }
#pragma unroll
    for (int i = 0; i < B_LOADS; ++i) {
      int sB = (i * NT + wave * 64) * 8;
      int s = sB + lane * 8;
      int row = s / BK;
      int blk = (s % BK) >> 3;
      gload16(B + (tn + row) * (long)ldb + kb + ((blk ^ (row & 7)) << 3), Bs + sB);
    }
    __syncthreads();
#pragma unroll
    for (int kk = 0; kk < BK; kk += 32) {
      bf16x8 af[FM], bfr[FN];
#pragma unroll
      for (int i = 0; i < FM; ++i) {
        int ar = wm0 + i * 16 + (lane & 15);
        int ac = kk + (lane >> 4) * 8;
        af[i] = *(const bf16x8*)(&As[ar * BK + (ac ^ ((ar & 7) << 3))]);
      }
#pragma unroll
      for (int j = 0; j < FN; ++j) {
        int br = wn0 + j * 16 + (lane & 15);
        int bc = kk + (lane >> 4) * 8;
        bfr[j] = *(const bf16x8*)(&Bs[br * BK + (bc ^ ((br & 7) << 3))]);
      }
#pragma unroll
      for (int i = 0; i < FM; ++i)
#pragma unroll
        for (int j = 0; j < FN; ++j)
          acc[i][j] = mfma16(af[i], bfr[j], acc[i][j]);
    }
    __syncthreads();
  }

#pragma unroll
  for (int i = 0; i < FM; ++i) {
#pragma unroll
    for (int j = 0; j < FN; ++j) {
      const long col = tn + wn0 + j * 16 + (lane & 15);
      float bv = BIAS ? bias[col] : 0.0f;
#pragma unroll
      for (int r = 0; r < 4; ++r) {
        const long row = tm + wm0 + i * 16 + (lane >> 4) * 4 + r;
        float v = acc[i][j][r] * scale + bv;
        if constexpr (MODE == 0) {
          ((float*)Cout)[row * (long)ldc + col] = v;
        } else if constexpr (MODE == 1) {
          ((u16*)Cout)[row * (long)ldc + col] = f2bf(v);
        } else if constexpr (MODE == 3) {
          float ge = 0.5f * v * (1.0f + erff(v * 0.70710678118654752f));
          ((u16*)Cout)[row * (long)ldc + col] = f2bf(ge);
        } else if constexpr (MODE == 4) {
          ((float*)Cout)[row * (long)ldc + col] = v + rowm[row * (long)ldc + col];
        } else {  // MODE 7: aggr finalize
          float dg = (float)auxI[row];
          float p2 = rowm[(size_t)row * 2048 + 1536 + col];
          float vv = (v + dg * (p2 + rowinv[col])) / fmaxf(dg, 1.0f);
          ((u16*)Cout)[row * (long)ldc + col] = f2bf(vv);
        }
      }
    }
  }
}

// ---------------- fused attention (2-pass, no P materialization) ----------------

// pass 1: rowsum[h][q] = sum_k exp(s/8). grid (N/32, H), 256 thr.
__global__ __launch_bounds__(256) void attn_rowsum(
    const u16* __restrict__ qkvb, float* __restrict__ rowsum)
{
  const int tid = threadIdx.x;
  const int lane = tid & 63;
  const int w = tid >> 6;
  const int q0 = blockIdx.x * 32;
  const int h = blockIdx.y;
  const int c = lane & 15, g = lane >> 4;
  bf16x8 aQ[2][2];
#pragma unroll
  for (int ti = 0; ti < 2; ++ti)
#pragma unroll
    for (int f = 0; f < 2; ++f)
      aQ[ti][f] = *(const bf16x8*)(qkvb + (size_t)(q0 + ti * 16 + c) * TD_ +
                                   h * 64 + f * 32 + g * 8);
  float part[2][4] = {};
  for (int kt = w * 128; kt < N_; kt += 512) {
#pragma unroll
    for (int kj = 0; kj < 8; ++kj) {
      bf16x8 bK[2];
#pragma unroll
      for (int f = 0; f < 2; ++f)
        bK[f] = *(const bf16x8*)(qkvb + (size_t)(kt + kj * 16 + c) * TD_ +
                                 512 + h * 64 + f * 32 + g * 8);
#pragma unroll
      for (int ti = 0; ti < 2; ++ti) {
        f32x4 s = {0.0f, 0.0f, 0.0f, 0.0f};
        s = mfma16(aQ[ti][0], bK[0], s);
        s = mfma16(aQ[ti][1], bK[1], s);
#pragma unroll
        for (int r = 0; r < 4; ++r) part[ti][r] += __expf(s[r] * 0.125f);
      }
    }
  }
#pragma unroll
  for (int m = 1; m <= 8; m <<= 1)
#pragma unroll
    for (int ti = 0; ti < 2; ++ti)
#pragma unroll
      for (int r = 0; r < 4; ++r) part[ti][r] += __shfl_xor(part[ti][r], m);
  if (c == 0) {
#pragma unroll
    for (int ti = 0; ti < 2; ++ti)
#pragma unroll
      for (int r = 0; r < 4; ++r)
        atomicAdd(&rowsum[(size_t)h * N_ + q0 + ti * 16 + g * 4 + r], part[ti][r]);
  }
}

// pass 2: recompute S, normalize, write attn-mean, PV into ctx.
// grid (N/32 q-tiles, N/512 k-chunks), 256 thr (4 waves).
__global__ __launch_bounds__(256) void attn_fused(
    const u16* __restrict__ qkvb, const u16* __restrict__ vT,
    const float* __restrict__ rowsum, float* __restrict__ ctx,
    float* __restrict__ attn)
{
  __shared__ u16 P[32 * 512];       // swizzled P tile (bf16)
  __shared__ float invs[H_][32];
  const int tid = threadIdx.x;
  const int lane = tid & 63;
  const int w = tid >> 6;
  const int q0 = blockIdx.x * 32;
  const int kc0 = blockIdx.y * 512;
  const int c = lane & 15, g = lane >> 4;
  if (tid < H_ * 32) {
    int hh = tid >> 5, qq = tid & 31;
    invs[hh][qq] = 1.0f / rowsum[(size_t)hh * N_ + q0 + qq];
  }
  __syncthreads();
  float att[2][8][4] = {};
  const int tiw = w & 1;
  const int djb = (w >> 1) * 2;
  for (int h = 0; h < H_; ++h) {
    // S phase: this wave covers k-cols [w*128, w*128+128)
    bf16x8 aQ[2][2];
#pragma unroll
    for (int ti = 0; ti < 2; ++ti)
#pragma unroll
      for (int f = 0; f < 2; ++f)
        aQ[ti][f] = *(const bf16x8*)(qkvb + (size_t)(q0 + ti * 16 + c) * TD_ +
                                     h * 64 + f * 32 + g * 8);
    f32x4 sacc[2][8];
#pragma unroll
    for (int ti = 0; ti < 2; ++ti)
#pragma unroll
      for (int kj = 0; kj < 8; ++kj) sacc[ti][kj] = (f32x4){0.0f, 0.0f, 0.0f, 0.0f};
#pragma unroll
    for (int kj = 0; kj < 8; ++kj) {
      bf16x8 bK[2];
#pragma unroll
      for (int f = 0; f < 2; ++f)
        bK[f] = *(const bf16x8*)(qkvb + (size_t)(kc0 + w * 128 + kj * 16 + c) * TD_ +
                                 512 + h * 64 + f * 32 + g * 8);
#pragma unroll
      for (int ti = 0; ti < 2; ++ti) {
        sacc[ti][kj] = mfma16(aQ[ti][0], bK[0], sacc[ti][kj]);
        sacc[ti][kj] = mfma16(aQ[ti][1], bK[1], sacc[ti][kj]);
      }
    }
    // normalize + head-mean accumulate + stage P (both-sides XOR swizzle)
#pragma unroll
    for (int ti = 0; ti < 2; ++ti) {
#pragma unroll
      for (int r = 0; r < 4; ++r) {
        const int row = ti * 16 + g * 4 + r;
        const float iv = invs[h][row];
#pragma unroll
        for (int kj = 0; kj < 8; ++kj) {
          float p = __expf(sacc[ti][kj][r] * 0.125f) * iv;
          att[ti][kj][r] += p;
          int col = w * 128 + kj * 16 + c;
          P[row * 512 + (col ^ ((row & 7) << 3))] = f2bf(p);
        }
      }
    }
    __syncthreads();
    // PV phase: wave computes ctx tiles (tiw, djb..djb+1) over this k-chunk
    f32x4 cacc[2] = {{0.0f, 0.0f, 0.0f, 0.0f}, {0.0f, 0.0f, 0.0f, 0.0f}};
    const int prow = tiw * 16 + c;
#pragma unroll
    for (int kb = 0; kb < 16; ++kb) {
      const int kcl = kb * 32 + g * 8;
      bf16x8 aP = *(const bf16x8*)(&P[prow * 512 + (kcl ^ ((prow & 7) << 3))]);
#pragma unroll
      for (int dj = 0; dj < 2; ++dj) {
        bf16x8 bV = *(const bf16x8*)(vT + (size_t)(h * 64 + (djb + dj) * 16 + c) * N_ +
                                     kc0 + kcl);
        cacc[dj] = mfma16(aP, bV, cacc[dj]);
      }
    }
#pragma unroll
    for (int dj = 0; dj < 2; ++dj)
#pragma unroll
      for (int r = 0; r < 4; ++r)
        atomicAdd(&ctx[(size_t)(q0 + tiw * 16 + g * 4 + r) * D_ +
                       h * 64 + (djb + dj) * 16 + c], cacc[dj][r]);
    __syncthreads();
  }
  // write head-mean attention weights
#pragma unroll
  for (int ti = 0; ti < 2; ++ti)
#pragma unroll
    for (int r = 0; r < 4; ++r) {
      const int row = q0 + ti * 16 + g * 4 + r;
#pragma unroll
      for (int kj = 0; kj < 8; ++kj)
        attn[(size_t)row * N_ + kc0 + w * 128 + kj * 16 + c] = att[ti][kj][r] * 0.125f;
    }
}

// ---------------- elementwise / CSR / reduction kernels ----------------

__global__ void conv_weights(const float* __restrict__ ip, const float* __restrict__ wih,
    const float* __restrict__ whh, const float* __restrict__ op,
    const float* __restrict__ f1, const float* __restrict__ f2, const float* __restrict__ mw,
    const float* __restrict__ gbhh,
    u16* __restrict__ ipb, u16* __restrict__ wihb, u16* __restrict__ whhb,
    u16* __restrict__ opb, u16* __restrict__ f1b, u16* __restrict__ f2b,
    u16* __restrict__ w1b, u16* __restrict__ w2b, float* __restrict__ biascat)
{
  int i = (blockIdx.x * 256 + threadIdx.x) * 4;
  if (i >= 5244928) return;
  if (i >= 5242880) {           // biascat[2048] = [gru_bhh | 0]
    int j = i - 5242880;
#pragma unroll
    for (int k = 0; k < 4; ++k) biascat[j + k] = (j + k < TD_) ? gbhh[j + k] : 0.0f;
    return;
  }
  if (i >= 4718592) {           // msg_w [512][1024] -> w1b | w2b
    int j = i - 4718592;
    int r = j >> 10, cc = j & 1023;
    f32x4 v = *(const f32x4*)(mw + j);
    u16* d = (cc < 512 ? w1b + r * 512 + cc : w2b + r * 512 + (cc - 512));
#pragma unroll
    for (int k = 0; k < 4; ++k) d[k] = f2bf(v[k]);
    return;
  }
  const float* src; u16* dst; int off;
  if      (i < 786432)  { src = ip;  dst = ipb;  off = i; }
  else if (i < 1572864) { src = wih; dst = wihb; off = i - 786432; }
  else if (i < 2359296) { src = whh; dst = whhb; off = i - 1572864; }
  else if (i < 2621440) { src = op;  dst = opb;  off = i - 2359296; }
  else if (i < 3670016) { src = f1;  dst = f1b;  off = i - 2621440; }
  else                  { src = f2;  dst = f2b;  off = i - 3670016; }
  f32x4 v = *(const f32x4*)(src + off);
#pragma unroll
  for (int k = 0; k < 4; ++k) dst[off + k] = f2bf(v[k]);
}

__global__ __launch_bounds__(1024) void transpose_bf16(const u16* __restrict__ src, int sld,
                                                       u16* __restrict__ dst, int dld) {
  __shared__ u16 tile[32][33];
  int r = blockIdx.y * 32 + threadIdx.y;
  int c = blockIdx.x * 32 + threadIdx.x;
  tile[threadIdx.y][threadIdx.x] = src[(size_t)r * sld + c];
  __syncthreads();
  int rr = blockIdx.x * 32 + threadIdx.y;
  int cc = blockIdx.y * 32 + threadIdx.x;
  dst[(size_t)rr * dld + cc] = tile[threadIdx.x][threadIdx.y];
}

__global__ void hist_kernel(const int* __restrict__ ei, int* __restrict__ degi) {
  int e = blockIdx.x * 256 + threadIdx.x;
  atomicAdd(&degi[ei[E_ + e]], 1);
}

__global__ __launch_bounds__(1024) void scan_kernel(const int* __restrict__ degi,
    int* __restrict__ rowstart, int* __restrict__ cursor) {
  __shared__ int sums[1024];
  int t = threadIdx.x;
  int b = t * 4;
  int d0 = degi[b], d1 = degi[b + 1], d2 = degi[b + 2], d3 = degi[b + 3];
  int tot = d0 + d1 + d2 + d3;
  sums[t] = tot;
  __syncthreads();
  for (int off = 1; off < 1024; off <<= 1) {
    int v = (t >= off) ? sums[t - off] : 0;
    __syncthreads();
    sums[t] += v;
    __syncthreads();
  }
  int excl = (t > 0) ? sums[t - 1] : 0;
  rowstart[b] = excl; rowstart[b + 1] = excl + d0;
  rowstart[b + 2] = excl + d0 + d1; rowstart[b + 3] = excl + d0 + d1 + d2;
  cursor[b] = excl; cursor[b + 1] = excl + d0;
  cursor[b + 2] = excl + d0 + d1; cursor[b + 3] = excl + d0 + d1 + d2;
  if (t == 1023) rowstart[N_] = excl + tot;
}

__global__ void scatter_kernel(const int* __restrict__ ei, int* __restrict__ cursor,
                               int* __restrict__ ss) {
  int e = blockIdx.x * 256 + threadIdx.x;
  int d = ei[E_ + e];
  int pos = atomicAdd(&cursor[d], 1);
  ss[pos] = ei[e];
}

__global__ __launch_bounds__(128) void gather_kernel(const int* __restrict__ rs,
    const int* __restrict__ ss, const u16* __restrict__ xn1b, u16* __restrict__ gsb) {
  int dst = blockIdx.x, t = threadIdx.x;
  int s0 = rs[dst], s1 = rs[dst + 1];
  __shared__ int sl[128];
  float a0 = 0, a1 = 0, a2 = 0, a3 = 0;
  for (int base = s0; base < s1; base += 128) {
    int n = min(128, s1 - base);
    if (t < n) sl[t] = ss[base + t];
    __syncthreads();
    for (int j = 0; j < n; ++j) {
      u16x4 v = *(const u16x4*)(xn1b + (size_t)sl[j] * D_ + t * 4);
      a0 += bf2f(v[0]); a1 += bf2f(v[1]); a2 += bf2f(v[2]); a3 += bf2f(v[3]);
    }
    __syncthreads();
  }
  u16* dp = gsb + (size_t)dst * D_ + t * 4;
  dp[0] = f2bf(a0); dp[1] = f2bf(a1); dp[2] = f2bf(a2); dp[3] = f2bf(a3);
}

__global__ __launch_bounds__(128) void ln12_kernel(const float* __restrict__ x,
    const float* __restrict__ g1, const float* __restrict__ b1,
    const float* __restrict__ g2, const float* __restrict__ b2,
    u16* __restrict__ xn1b, u16* __restrict__ xn2b)
{
  int row = blockIdx.x, t = threadIdx.x;
  size_t base = (size_t)row * D_ + t * 4;
  f32x4 v = *(const f32x4*)(x + base);
  float s = v[0] + v[1] + v[2] + v[3];
  float ss = v[0]*v[0] + v[1]*v[1] + v[2]*v[2] + v[3]*v[3];
  __shared__ float red[4];
  for (int off = 32; off; off >>= 1) { s += __shfl_down(s, off); ss += __shfl_down(ss, off); }
  if ((t & 63) == 0) { red[t >> 6] = s; red[2 + (t >> 6)] = ss; }
  __syncthreads();
  s = red[0] + red[1]; ss = red[2] + red[3];
  float mu = s * (1.0f / D_);
  float inv = rsqrtf(ss * (1.0f / D_) - mu * mu + 1e-5f);
#pragma unroll
  for (int i = 0; i < 4; ++i) {
    int c = t * 4 + i;
    float xh = (v[i] - mu) * inv;
    xn1b[base + i] = f2bf(xh * g1[c] + b1[c]);
    xn2b[base + i] = f2bf(xh * g2[c] + b2[c]);
  }
}

__global__ void gru_kernel(const float* __restrict__ gi, const float* __restrict__ ghp,
                           const u16* __restrict__ xn1b, float* __restrict__ xm) {
  int i = blockIdx.x * 256 + threadIdx.x;
  int n = i >> 9, d = i & 511;
  size_t bi = (size_t)n * TD_ + d;
  size_t bh = (size_t)n * 2048 + d;
  float ir = gi[bi], iz = gi[bi + 512], in_ = gi[bi + 1024];
  float hr = ghp[bh], hz = ghp[bh + 512], hn = ghp[bh + 1024];
  float r = 1.0f / (1.0f + expf(-(ir + hr)));
  float z = 1.0f / (1.0f + expf(-(iz + hz)));
  float nn = tanhf(in_ + r * hn);
  xm[i] = (1.0f - z) * nn + z * bf2f(xn1b[i]);
}

__global__ __launch_bounds__(128) void combine_ln3(const float* __restrict__ x,
    const float* __restrict__ xm, const float* __restrict__ xa,
    const float* __restrict__ gw, const float* __restrict__ gb,
    const float* __restrict__ g3, const float* __restrict__ b3,
    float* __restrict__ xc, u16* __restrict__ xn3b)
{
  int row = blockIdx.x, t = threadIdx.x;
  size_t base = (size_t)row * D_ + t * 4;
  f32x4 xv = *(const f32x4*)(x + base);
  f32x4 mv = *(const f32x4*)(xm + base);
  f32x4 av = *(const f32x4*)(xa + base);
  __shared__ float red[4];
  float gs = 0.0f;
#pragma unroll
  for (int i = 0; i < 4; ++i) { int c = t * 4 + i; gs += mv[i] * gw[c] + av[i] * gw[D_ + c]; }
  for (int off = 32; off; off >>= 1) gs += __shfl_down(gs, off);
  if ((t & 63) == 0) red[t >> 6] = gs;
  __syncthreads();
  float g = 1.0f / (1.0f + expf(-(red[0] + red[1] + gb[0])));
  __syncthreads();
  f32x4 cv = xv + g * mv + (1.0f - g) * av;
  *(f32x4*)(xc + base) = cv;
  float s = cv[0] + cv[1] + cv[2] + cv[3];
  float ss = cv[0]*cv[0] + cv[1]*cv[1] + cv[2]*cv[2] + cv[3]*cv[3];
  for (int off = 32; off; off >>= 1) { s += __shfl_down(s, off); ss += __shfl_down(ss, off); }
  if ((t & 63) == 0) { red[t >> 6] = s; red[2 + (t >> 6)] = ss; }
  __syncthreads();
  s = red[0] + red[1]; ss = red[2] + red[3];
  float mu = s * (1.0f / D_);
  float inv = rsqrtf(ss * (1.0f / D_) - mu * mu + 1e-5f);
#pragma unroll
  for (int i = 0; i < 4; ++i) {
    int c = t * 4 + i;
    float xh = (cv[i] - mu) * inv;
    xn3b[base + i] = f2bf(xh * g3[c] + b3[c]);
  }
}

// ------------------------------ launch ------------------------------

extern "C" void kernel_launch(void* const* d_in, const int* in_sizes, int n_in,
                              void* d_out, int out_size, void* d_ws, size_t ws_size,
                              hipStream_t stream)
{
  (void)in_sizes; (void)n_in; (void)out_size;
  const float* x         = (const float*)d_in[0];
  const int*   ei        = (const int*)d_in[1];
  const float* ln1_g     = (const float*)d_in[2];
  const float* ln1_b     = (const float*)d_in[3];
  const float* ln2_g     = (const float*)d_in[4];
  const float* ln2_b     = (const float*)d_in[5];
  const float* ln3_g     = (const float*)d_in[6];
  const float* ln3_b     = (const float*)d_in[7];
  const float* in_proj_w = (const float*)d_in[8];
  const float* in_proj_b = (const float*)d_in[9];
  const float* out_proj_w= (const float*)d_in[10];
  const float* out_proj_b= (const float*)d_in[11];
  const float* msg_w     = (const float*)d_in[12];
  const float* msg_b     = (const float*)d_in[13];
  const float* gru_wih   = (const float*)d_in[14];
  const float* gru_whh   = (const float*)d_in[15];
  const float* gru_bih   = (const float*)d_in[16];
  const float* gru_bhh   = (const float*)d_in[17];
  const float* ffn_w1    = (const float*)d_in[18];
  const float* ffn_b1    = (const float*)d_in[19];
  const float* ffn_w2    = (const float*)d_in[20];
  const float* ffn_b2    = (const float*)d_in[21];
  const float* gate_w    = (const float*)d_in[22];
  const float* gate_b    = (const float*)d_in[23];

  char* ws = (char*)d_ws;
  size_t o = 0;
  auto alloc = [&](size_t b) { size_t r = o; o += (b + 255) & ~(size_t)255; return r; };
  const size_t o_xn1b  = alloc((size_t)N_ * D_ * 2);
  const size_t o_xn2b  = alloc((size_t)N_ * D_ * 2);
  const size_t o_ipb   = alloc((size_t)TD_ * D_ * 2);
  const size_t o_w1b   = alloc((size_t)D_ * D_ * 2);
  const size_t o_wihb  = alloc((size_t)TD_ * D_ * 2);
  const size_t o_whhb  = alloc((size_t)TD_ * D_ * 2);  // whhb & w2b adjacent: [whh|W2]
  const size_t o_w2b   = alloc((size_t)D_ * D_ * 2);
  const size_t o_opb   = alloc((size_t)D_ * D_ * 2);
  const size_t o_f1b   = alloc((size_t)FD_ * D_ * 2);
  const size_t o_f2b   = alloc((size_t)D_ * FD_ * 2);
  const size_t o_bcat  = alloc((size_t)2048 * 4);
  const size_t o_degi  = alloc((size_t)N_ * 4);
  const size_t o_rs    = alloc((size_t)(N_ + 1) * 4);
  const size_t o_cur   = alloc((size_t)N_ * 4);
  const size_t o_ss    = alloc((size_t)E_ * 4);
  const size_t o_rsum  = alloc((size_t)H_ * N_ * 4);
  const size_t o_aggrb = alloc((size_t)N_ * D_ * 2);
  const size_t o_gsb   = alloc((size_t)N_ * D_ * 2);
  const size_t o_xm    = alloc((size_t)N_ * D_ * 4);
  const size_t o_xn3b  = alloc((size_t)N_ * D_ * 2);
  const size_t o_big2  = alloc((size_t)N_ * FD_ * 2);       // h1b
  const size_t o_rn    = alloc((size_t)N_ * TD_ * 4);       // gi -> qkvb+vT+ctx
  const size_t o_ro    = alloc((size_t)N_ * 2048 * 4);      // ghp -> xattn+xc
  if (ws_size < o) return;

  u16* xn1b   = (u16*)(ws + o_xn1b);
  u16* xn2b   = (u16*)(ws + o_xn2b);
  u16* ipb    = (u16*)(ws + o_ipb);
  u16* w1b    = (u16*)(ws + o_w1b);
  u16* wihb   = (u16*)(ws + o_wihb);
  u16* whhb   = (u16*)(ws + o_whhb);
  u16* w2b    = (u16*)(ws + o_w2b);
  u16* opb    = (u16*)(ws + o_opb);
  u16* f1b    = (u16*)(ws + o_f1b);
  u16* f2b    = (u16*)(ws + o_f2b);
  float* bcat = (float*)(ws + o_bcat);
  int* degi   = (int*)(ws + o_degi);
  int* rs     = (int*)(ws + o_rs);
  int* cur    = (int*)(ws + o_cur);
  int* ssrc   = (int*)(ws + o_ss);
  float* rsum = (float*)(ws + o_rsum);
  u16* aggrb  = (u16*)(ws + o_aggrb);
  u16* gsb    = (u16*)(ws + o_gsb);
  float* xm   = (float*)(ws + o_xm);
  u16* xn3b   = (u16*)(ws + o_xn3b);
  u16* h1b    = (u16*)(ws + o_big2);
  float* gi   = (float*)(ws + o_rn);
  u16* qkvb   = (u16*)(ws + o_rn);
  u16* vT     = (u16*)(ws + o_rn + (size_t)N_ * TD_ * 2);
  float* ctx  = (float*)(ws + o_rn + (size_t)N_ * TD_ * 2 + (size_t)D_ * N_ * 2);
  float* ghp  = (float*)(ws + o_ro);
  float* xattn= (float*)(ws + o_ro);
  float* xc   = (float*)(ws + o_ro + (size_t)N_ * D_ * 4);

  float* outp = (float*)d_out;
  float* attn = (float*)d_out + (size_t)N_ * D_;

  hipMemsetAsync(degi, 0, (size_t)N_ * 4, stream);
  hipMemsetAsync(rsum, 0, (size_t)H_ * N_ * 4, stream);

  conv_weights<<<5122, 256, 0, stream>>>(in_proj_w, gru_wih, gru_whh, out_proj_w,
                                         ffn_w1, ffn_w2, msg_w, gru_bhh,
                                         ipb, wihb, whhb, opb, f1b, f2b, w1b, w2b, bcat);

  ln12_kernel<<<N_, 128, 0, stream>>>(x, ln1_g, ln1_b, ln2_g, ln2_b, xn1b, xn2b);

  // CSR build + sparse gather-sum
  hist_kernel<<<512, 256, 0, stream>>>(ei, degi);
  scan_kernel<<<1, 1024, 0, stream>>>(degi, rs, cur);
  scatter_kernel<<<512, 256, 0, stream>>>(ei, cur, ssrc);
  gather_kernel<<<N_, 128, 0, stream>>>(rs, ssrc, xn1b, gsb);

  // ghp = xn1 @ [whh | W2]^T + [bhh | 0]
  gemm_bt<128, 128, 64, 2, 2, 4, 4, 0, true, 0><<<dim3(32, 16), 256, 0, stream>>>(
      xn1b, D_, whhb, D_, ghp, 2048, bcat, 1.0f, D_, nullptr, nullptr, nullptr);
  // aggr = finalize(gather_sum @ W1^T)  (MODE 7)
  gemm_bt<64, 64, 64, 2, 2, 2, 2, 7, false, 0><<<dim3(64, 8), 256, 0, stream>>>(
      gsb, D_, w1b, D_, aggrb, D_, nullptr, 1.0f, D_, ghp, msg_b, degi);

  // GRU input gates + update
  gemm_bt<128, 128, 64, 2, 2, 4, 4, 0, true, 0><<<dim3(32, 12), 256, 0, stream>>>(
      aggrb, D_, wihb, D_, gi, TD_, gru_bih, 1.0f, D_, nullptr, nullptr, nullptr);
  gru_kernel<<<8192, 256, 0, stream>>>(gi, ghp, xn1b, xm);

  // qkv projection (gi region now dead)
  gemm_bt<128, 128, 64, 2, 2, 4, 4, 1, true, 0><<<dim3(32, 12), 256, 0, stream>>>(
      xn2b, D_, ipb, D_, qkvb, TD_, in_proj_b, 1.0f, D_, nullptr, nullptr, nullptr);
  transpose_bf16<<<dim3(16, 128), dim3(32, 32), 0, stream>>>(qkvb + 1024, TD_, vT, N_);
  hipMemsetAsync(ctx, 0, (size_t)N_ * D_ * 4, stream);

  // fused attention: rowsum pass then recompute+mean+PV pass
  attn_rowsum<<<dim3(N_ / 32, H_), 256, 0, stream>>>(qkvb, rsum);
  attn_fused<<<dim3(N_ / 32, N_ / 512), 256, 0, stream>>>(qkvb, vT, rsum, ctx, attn);

  // out_proj (ctx f32 cast-staged)
  gemm_bt<64, 64, 64, 2, 2, 2, 2, 0, true, 2><<<dim3(64, 8), 256, 0, stream>>>(
      (const u16*)ctx, D_, opb, D_, xattn, D_, out_proj_b, 1.0f, D_,
      nullptr, nullptr, nullptr);

  combine_ln3<<<N_, 128, 0, stream>>>(x, xm, xattn, gate_w, gate_b, ln3_g, ln3_b, xc, xn3b);

  // FFN: GELU fused; residual fused in FFN2 epilogue
  gemm_bt<128, 128, 64, 2, 2, 4, 4, 3, true, 0><<<dim3(32, 16), 256, 0, stream>>>(
      xn3b, D_, f1b, D_, h1b, FD_, ffn_b1, 1.0f, D_, nullptr, nullptr, nullptr);
  gemm_bt<64, 64, 64, 2, 2, 2, 2, 4, true, 0><<<dim3(64, 8), 256, 0, stream>>>(
      h1b, FD_, f2b, FD_, outp, D_, ffn_b2, 1.0f, FD_, xc, nullptr, nullptr);
}

// Round 8
// 535.718 us; speedup vs baseline: 1.4758x; 1.4758x over previous
//
#include <hip/hip_runtime.h>
#include <stdint.h>

#define N_ 4096
#define D_ 512
#define H_ 8
#define E_ 131072
#define TD_ 1536
#define FD_ 2048
#define CM_ 2048  // attention row-chunk (2 chunks)

typedef unsigned short u16;
typedef __bf16 bf16x8 __attribute__((ext_vector_type(8)));
typedef u16 u16x8 __attribute__((ext_vector_type(8)));
typedef u16 u16x4 __attribute__((ext_vector_type(4)));
typedef float f32x4 __attribute__((ext_vector_type(4)));

__device__ __forceinline__ u16 f2bf(float f) {
  union { float f; uint32_t u; } v; v.f = f;
  return (u16)((v.u + 0x7FFFu + ((v.u >> 16) & 1u)) >> 16);
}
__device__ __forceinline__ float bf2f(u16 b) {
  union { uint32_t u; float f; } v; v.u = ((uint32_t)b) << 16; return v.f;
}

__device__ __forceinline__ void gload16(const u16* g, u16* l) {
  __builtin_amdgcn_global_load_lds(
      (const __attribute__((address_space(1))) void*)(uintptr_t)g,
      (__attribute__((address_space(3))) void*)(uint32_t)(uintptr_t)l, 16, 0, 0);
}

// ---------------- GEMM: C[M,N] = A[M,K] @ B[N,K]^T (+bias) -----------------
// MODE: 0 f32 store, 1 bf16 store, 2 f32 atomicAdd, 3 GELU bf16 (sigmoid form),
//       4 f32 store of (v + rowm[row*ldc+col])  (residual),
//       5 bf16 store of exp(v) + per-row sum atomicAdd into rowm[h*CM_+row],
//       6 f32 atomicAdd of v * rowinv[h*CM_+row]  (PV with softmax denom),
//       7 bf16 store of (v + deg*(ghp_part2 + msg_b)) / max(deg,1)  (aggr)
// HM: 0 none (y=N-block, z=split-K); 1 z=head (A/B/C shifted); 2 y=head, z=split-K
// AMODE: 0 A bf16 via global_load_lds (source-swizzled); 2 A f32 cast->bf16 (reg-staged)
template <int BM, int BN, int BK, int WM, int WN, int FM, int FN, int MODE, bool BIAS,
          int HM, int AMODE>
__global__ __launch_bounds__(WM * WN * 64) void gemm_bt(
    const u16* __restrict__ A, int lda, const u16* __restrict__ B, int ldb,
    void* __restrict__ Cout, int ldc, const float* __restrict__ bias,
    float scale, int Kchunk, size_t hA, size_t hB, size_t hC,
    float* __restrict__ rowm, const float* __restrict__ rowinv,
    const int* __restrict__ auxI)
{
  static_assert(BM == WM * FM * 16 && BN == WN * FN * 16, "tile shape");
  static_assert(BK == 64, "LDS swizzle assumes BK=64");
  __shared__ alignas(16) u16 As[BM * BK];
  __shared__ alignas(16) u16 Bs[BN * BK];
  __shared__ float rsum[2][BM];   // only used by MODE 5
  constexpr int NT = WM * WN * 64;
  const int tid = threadIdx.x;
  const int lane = tid & 63;
  const int wave = tid >> 6;
  const long tm = (long)blockIdx.x * BM;
  long tn, k0;
  size_t cOff = 0;
  int hIdx = 0;
  if constexpr (HM == 1) {
    hIdx = blockIdx.z;
    A += (size_t)blockIdx.z * hA; B += (size_t)blockIdx.z * hB; cOff = (size_t)blockIdx.z * hC;
    tn = (long)blockIdx.y * BN; k0 = 0;
  } else if constexpr (HM == 2) {
    hIdx = blockIdx.y;
    A += (size_t)blockIdx.y * hA; B += (size_t)blockIdx.y * hB; cOff = (size_t)blockIdx.y * hC;
    tn = 0; k0 = (long)blockIdx.z * Kchunk;
  } else {
    tn = (long)blockIdx.y * BN; k0 = (long)blockIdx.z * Kchunk;
  }
  const int wm0 = (wave / WN) * (FM * 16);
  const int wn0 = (wave % WN) * (FN * 16);

  f32x4 acc[FM][FN] = {};

  constexpr int A_LOADS = (BM * BK) / (NT * 8);
  constexpr int B_LOADS = (BN * BK) / (NT * 8);

  for (int kt = 0; kt < Kchunk; kt += BK) {
    const long kb = k0 + kt;
#pragma unroll
    for (int i = 0; i < A_LOADS; ++i) {
      if constexpr (AMODE == 0) {
        int sB = (i * NT + wave * 64) * 8;
        int s = sB + lane * 8;
        int row = s / BK;
        int blk = (s % BK) >> 3;
        gload16(A + (tm + row) * (long)lda + kb + ((blk ^ (row & 7)) << 3), As + sB);
      } else {
        int s = (i * NT + tid) * 8;
        int row = s / BK, kk = s % BK;
        const float* Af = (const float*)A;
        f32x4 lo = *(const f32x4*)(Af + (tm + row) * (long)lda + kb + kk);
        f32x4 hi = *(const f32x4*)(Af + (tm + row) * (long)lda + kb + kk + 4);
        u16x8 w;
#pragma unroll
        for (int k = 0; k < 4; ++k) { w[k] = f2bf(lo[k]); w[4 + k] = f2bf(hi[k]); }
        *(u16x8*)(&As[row * BK + (kk ^ ((row & 7) << 3))]) = w;
      }
    }
#pragma unroll
    for (int i = 0; i < B_LOADS; ++i) {
      int sB = (i * NT + wave * 64) * 8;
      int s = sB + lane * 8;
      int row = s / BK;
      int blk = (s % BK) >> 3;
      gload16(B + (tn + row) * (long)ldb + kb + ((blk ^ (row & 7)) << 3), Bs + sB);
    }
    __syncthreads();
#pragma unroll
    for (int kk = 0; kk < BK; kk += 32) {
      bf16x8 af[FM], bfr[FN];
#pragma unroll
      for (int i = 0; i < FM; ++i) {
        int ar = wm0 + i * 16 + (lane & 15);
        int ac = kk + (lane >> 4) * 8;
        af[i] = *(const bf16x8*)(&As[ar * BK + (ac ^ ((ar & 7) << 3))]);
      }
#pragma unroll
      for (int j = 0; j < FN; ++j) {
        int br = wn0 + j * 16 + (lane & 15);
        int bc = kk + (lane >> 4) * 8;
        bfr[j] = *(const bf16x8*)(&Bs[br * BK + (bc ^ ((br & 7) << 3))]);
      }
#pragma unroll
      for (int i = 0; i < FM; ++i)
#pragma unroll
        for (int j = 0; j < FN; ++j)
          acc[i][j] = __builtin_amdgcn_mfma_f32_16x16x32_bf16(af[i], bfr[j], acc[i][j], 0, 0, 0);
    }
    __syncthreads();
  }

  if constexpr (MODE == 5) {
    // exp + per-row sum: write P' = exp(acc*scale), reduce rows into rowm
#pragma unroll
    for (int i = 0; i < FM; ++i) {
      float part[4] = {0.0f, 0.0f, 0.0f, 0.0f};
#pragma unroll
      for (int j = 0; j < FN; ++j) {
        const long col = tn + wn0 + j * 16 + (lane & 15);
#pragma unroll
        for (int r = 0; r < 4; ++r) {
          const long row = tm + wm0 + i * 16 + (lane >> 4) * 4 + r;
          float p = __expf(acc[i][j][r] * scale);
          ((u16*)Cout)[cOff + row * (long)ldc + col] = f2bf(p);
          part[r] += p;
        }
      }
#pragma unroll
      for (int r = 0; r < 4; ++r) {
        float s = part[r];
        s += __shfl_xor(s, 1); s += __shfl_xor(s, 2);
        s += __shfl_xor(s, 4); s += __shfl_xor(s, 8);
        if ((lane & 15) == 0)
          rsum[wave & 1][wm0 + i * 16 + (lane >> 4) * 4 + r] = s;
      }
    }
    __syncthreads();
    for (int t = tid; t < BM; t += NT)
      atomicAdd(&rowm[(size_t)hIdx * CM_ + tm + t], rsum[0][t] + rsum[1][t]);
    return;
  }

#pragma unroll
  for (int i = 0; i < FM; ++i) {
#pragma unroll
    for (int j = 0; j < FN; ++j) {
      const long col = tn + wn0 + j * 16 + (lane & 15);
      float bv = 0.0f;
      if constexpr (BIAS) {
        if (MODE != 2 || blockIdx.z == 0) bv = bias[col];
      }
#pragma unroll
      for (int r = 0; r < 4; ++r) {
        const long row = tm + wm0 + i * 16 + (lane >> 4) * 4 + r;
        float v = acc[i][j][r] * scale + bv;
        if constexpr (MODE == 0) {
          ((float*)Cout)[cOff + row * (long)ldc + col] = v;
        } else if constexpr (MODE == 1) {
          ((u16*)Cout)[cOff + row * (long)ldc + col] = f2bf(v);
        } else if constexpr (MODE == 2) {
          atomicAdd(&((float*)Cout)[cOff + row * (long)ldc + col], v);
        } else if constexpr (MODE == 3) {
          // GELU tanh-approx in sigmoid form: v * sigmoid(1.595769122*(v + 0.044715 v^3))
          float u = 1.595769122f * (v + 0.044715f * v * v * v);
          float ge = v / (1.0f + __expf(-u));
          ((u16*)Cout)[cOff + row * (long)ldc + col] = f2bf(ge);
        } else if constexpr (MODE == 4) {
          ((float*)Cout)[cOff + row * (long)ldc + col] = v + rowm[row * (long)ldc + col];
        } else if constexpr (MODE == 6) {
          atomicAdd(&((float*)Cout)[cOff + row * (long)ldc + col],
                    v * rowinv[(size_t)hIdx * CM_ + row]);
        } else {  // MODE 7: aggr finalize
          float dg = (float)auxI[row];
          float p2 = rowm[(size_t)row * 2048 + 1536 + col];
          float vv = (v + dg * (p2 + rowinv[col])) / fmaxf(dg, 1.0f);
          ((u16*)Cout)[cOff + row * (long)ldc + col] = f2bf(vv);
        }
      }
    }
  }
}

// ---------------- elementwise / CSR / reduction kernels ----------------

__global__ void conv_weights(const float* __restrict__ ip, const float* __restrict__ wih,
    const float* __restrict__ whh, const float* __restrict__ op,
    const float* __restrict__ f1, const float* __restrict__ f2, const float* __restrict__ mw,
    const float* __restrict__ gbhh,
    u16* __restrict__ ipb, u16* __restrict__ wihb, u16* __restrict__ whhb,
    u16* __restrict__ opb, u16* __restrict__ f1b, u16* __restrict__ f2b,
    u16* __restrict__ w1b, u16* __restrict__ w2b, float* __restrict__ biascat)
{
  int i = (blockIdx.x * 256 + threadIdx.x) * 4;
  if (i >= 5244928) return;
  if (i >= 5242880) {           // biascat[2048] = [gru_bhh | 0]
    int j = i - 5242880;
#pragma unroll
    for (int k = 0; k < 4; ++k) biascat[j + k] = (j + k < TD_) ? gbhh[j + k] : 0.0f;
    return;
  }
  if (i >= 4718592) {           // msg_w [512][1024] -> w1b | w2b
    int j = i - 4718592;
    int r = j >> 10, c = j & 1023;
    f32x4 v = *(const f32x4*)(mw + j);
    u16* d = (c < 512 ? w1b + r * 512 + c : w2b + r * 512 + (c - 512));
#pragma unroll
    for (int k = 0; k < 4; ++k) d[k] = f2bf(v[k]);
    return;
  }
  const float* src; u16* dst; int off;
  if      (i < 786432)  { src = ip;  dst = ipb;  off = i; }
  else if (i < 1572864) { src = wih; dst = wihb; off = i - 786432; }
  else if (i < 2359296) { src = whh; dst = whhb; off = i - 1572864; }
  else if (i < 2621440) { src = op;  dst = opb;  off = i - 2359296; }
  else if (i < 3670016) { src = f1;  dst = f1b;  off = i - 2621440; }
  else                  { src = f2;  dst = f2b;  off = i - 3670016; }
  f32x4 v = *(const f32x4*)(src + off);
#pragma unroll
  for (int k = 0; k < 4; ++k) dst[off + k] = f2bf(v[k]);
}

__global__ __launch_bounds__(1024) void transpose_bf16(const u16* __restrict__ src, int sld,
                                                       u16* __restrict__ dst, int dld) {
  __shared__ u16 tile[32][33];
  int r = blockIdx.y * 32 + threadIdx.y;
  int c = blockIdx.x * 32 + threadIdx.x;
  tile[threadIdx.y][threadIdx.x] = src[(size_t)r * sld + c];
  __syncthreads();
  int rr = blockIdx.x * 32 + threadIdx.y;
  int cc = blockIdx.y * 32 + threadIdx.x;
  dst[(size_t)rr * dld + cc] = tile[threadIdx.x][threadIdx.y];
}

__global__ void hist_kernel(const int* __restrict__ ei, int* __restrict__ degi) {
  int e = blockIdx.x * 256 + threadIdx.x;
  atomicAdd(&degi[ei[E_ + e]], 1);
}

__global__ __launch_bounds__(1024) void scan_kernel(const int* __restrict__ degi,
    int* __restrict__ rowstart, int* __restrict__ cursor) {
  __shared__ int sums[1024];
  int t = threadIdx.x;
  int b = t * 4;
  int d0 = degi[b], d1 = degi[b + 1], d2 = degi[b + 2], d3 = degi[b + 3];
  int tot = d0 + d1 + d2 + d3;
  sums[t] = tot;
  __syncthreads();
  for (int off = 1; off < 1024; off <<= 1) {
    int v = (t >= off) ? sums[t - off] : 0;
    __syncthreads();
    sums[t] += v;
    __syncthreads();
  }
  int excl = (t > 0) ? sums[t - 1] : 0;
  rowstart[b] = excl; rowstart[b + 1] = excl + d0;
  rowstart[b + 2] = excl + d0 + d1; rowstart[b + 3] = excl + d0 + d1 + d2;
  cursor[b] = excl; cursor[b + 1] = excl + d0;
  cursor[b + 2] = excl + d0 + d1; cursor[b + 3] = excl + d0 + d1 + d2;
  if (t == 1023) rowstart[N_] = excl + tot;
}

__global__ void scatter_kernel(const int* __restrict__ ei, int* __restrict__ cursor,
                               int* __restrict__ ss) {
  int e = blockIdx.x * 256 + threadIdx.x;
  int d = ei[E_ + e];
  int pos = atomicAdd(&cursor[d], 1);
  ss[pos] = ei[e];
}

// per-dst gather-sum of xn1 rows (bf16 in, f32 accum), bf16 out
__global__ __launch_bounds__(128) void gather_kernel(const int* __restrict__ rs,
    const int* __restrict__ ss, const u16* __restrict__ xn1b, u16* __restrict__ gsb) {
  int dst = blockIdx.x, t = threadIdx.x;
  int s0 = rs[dst], s1 = rs[dst + 1];
  __shared__ int sl[128];
  float a0 = 0, a1 = 0, a2 = 0, a3 = 0;
  for (int base = s0; base < s1; base += 128) {
    int n = min(128, s1 - base);
    if (t < n) sl[t] = ss[base + t];
    __syncthreads();
    for (int j = 0; j < n; ++j) {
      u16x4 v = *(const u16x4*)(xn1b + (size_t)sl[j] * D_ + t * 4);
      a0 += bf2f(v[0]); a1 += bf2f(v[1]); a2 += bf2f(v[2]); a3 += bf2f(v[3]);
    }
    __syncthreads();
  }
  u16* dp = gsb + (size_t)dst * D_ + t * 4;
  dp[0] = f2bf(a0); dp[1] = f2bf(a1); dp[2] = f2bf(a2); dp[3] = f2bf(a3);
}

__global__ __launch_bounds__(128) void ln12_kernel(const float* __restrict__ x,
    const float* __restrict__ g1, const float* __restrict__ b1,
    const float* __restrict__ g2, const float* __restrict__ b2,
    u16* __restrict__ xn1b, u16* __restrict__ xn2b)
{
  int row = blockIdx.x, t = threadIdx.x;
  size_t base = (size_t)row * D_ + t * 4;
  f32x4 v = *(const f32x4*)(x + base);
  float s = v[0] + v[1] + v[2] + v[3];
  float ss = v[0]*v[0] + v[1]*v[1] + v[2]*v[2] + v[3]*v[3];
  __shared__ float red[4];
  for (int off = 32; off; off >>= 1) { s += __shfl_down(s, off); ss += __shfl_down(ss, off); }
  if ((t & 63) == 0) { red[t >> 6] = s; red[2 + (t >> 6)] = ss; }
  __syncthreads();
  s = red[0] + red[1]; ss = red[2] + red[3];
  float mu = s * (1.0f / D_);
  float inv = rsqrtf(ss * (1.0f / D_) - mu * mu + 1e-5f);
#pragma unroll
  for (int i = 0; i < 4; ++i) {
    int c = t * 4 + i;
    float xh = (v[i] - mu) * inv;
    xn1b[base + i] = f2bf(xh * g1[c] + b1[c]);
    xn2b[base + i] = f2bf(xh * g2[c] + b2[c]);
  }
}

__global__ void gru_kernel(const float* __restrict__ gi, const float* __restrict__ ghp,
                           const u16* __restrict__ xn1b, float* __restrict__ xm) {
  int i = blockIdx.x * 256 + threadIdx.x;
  int n = i >> 9, d = i & 511;
  size_t bi = (size_t)n * TD_ + d;
  size_t bh = (size_t)n * 2048 + d;
  float ir = gi[bi], iz = gi[bi + 512], in_ = gi[bi + 1024];
  float hr = ghp[bh], hz = ghp[bh + 512], hn = ghp[bh + 1024];
  float r = 1.0f / (1.0f + expf(-(ir + hr)));
  float z = 1.0f / (1.0f + expf(-(iz + hz)));
  float nn = tanhf(in_ + r * hn);
  xm[i] = (1.0f - z) * nn + z * bf2f(xn1b[i]);
}

// attn[q,:] = (1/8) sum_h P'_h[q,:] / rowsum_h[q]; also writes rinv = 1/rowsum
__global__ __launch_bounds__(256) void mean_kernel(const u16* __restrict__ sc,
    const float* __restrict__ rowsum, float* __restrict__ rinv,
    float* __restrict__ attn) {
  const int row = blockIdx.x, t = threadIdx.x;
  float am[16] = {};
  for (int h = 0; h < H_; ++h) {
    const u16* wr = sc + (size_t)h * ((size_t)CM_ * N_) + (size_t)row * N_ + t * 16;
    float inv = 0.125f / rowsum[(size_t)h * CM_ + row];
    if (t == 0) rinv[(size_t)h * CM_ + row] = inv * 8.0f;
    u16x8 v0 = *(const u16x8*)(wr);
    u16x8 v1 = *(const u16x8*)(wr + 8);
#pragma unroll
    for (int i = 0; i < 8; ++i) { am[i] += bf2f(v0[i]) * inv; am[8 + i] += bf2f(v1[i]) * inv; }
  }
  float* ar = attn + (size_t)row * N_ + t * 16;
#pragma unroll
  for (int i = 0; i < 16; ++i) ar[i] = am[i];
}

// gated combine (gate fused) + LN3
__global__ __launch_bounds__(128) void combine_ln3(const float* __restrict__ x,
    const float* __restrict__ xm, const float* __restrict__ xa,
    const float* __restrict__ gw, const float* __restrict__ gb,
    const float* __restrict__ g3, const float* __restrict__ b3,
    float* __restrict__ xc, u16* __restrict__ xn3b)
{
  int row = blockIdx.x, t = threadIdx.x;
  size_t base = (size_t)row * D_ + t * 4;
  f32x4 xv = *(const f32x4*)(x + base);
  f32x4 mv = *(const f32x4*)(xm + base);
  f32x4 av = *(const f32x4*)(xa + base);
  __shared__ float red[4];
  float gs = 0.0f;
#pragma unroll
  for (int i = 0; i < 4; ++i) { int c = t * 4 + i; gs += mv[i] * gw[c] + av[i] * gw[D_ + c]; }
  for (int off = 32; off; off >>= 1) gs += __shfl_down(gs, off);
  if ((t & 63) == 0) red[t >> 6] = gs;
  __syncthreads();
  float g = 1.0f / (1.0f + expf(-(red[0] + red[1] + gb[0])));
  __syncthreads();
  f32x4 cv = xv + g * mv + (1.0f - g) * av;
  *(f32x4*)(xc + base) = cv;
  float s = cv[0] + cv[1] + cv[2] + cv[3];
  float ss = cv[0]*cv[0] + cv[1]*cv[1] + cv[2]*cv[2] + cv[3]*cv[3];
  for (int off = 32; off; off >>= 1) { s += __shfl_down(s, off); ss += __shfl_down(ss, off); }
  if ((t & 63) == 0) { red[t >> 6] = s; red[2 + (t >> 6)] = ss; }
  __syncthreads();
  s = red[0] + red[1]; ss = red[2] + red[3];
  float mu = s * (1.0f / D_);
  float inv = rsqrtf(ss * (1.0f / D_) - mu * mu + 1e-5f);
#pragma unroll
  for (int i = 0; i < 4; ++i) {
    int c = t * 4 + i;
    float xh = (cv[i] - mu) * inv;
    xn3b[base + i] = f2bf(xh * g3[c] + b3[c]);
  }
}

// ------------------------------ launch ------------------------------

extern "C" void kernel_launch(void* const* d_in, const int* in_sizes, int n_in,
                              void* d_out, int out_size, void* d_ws, size_t ws_size,
                              hipStream_t stream)
{
  (void)in_sizes; (void)n_in; (void)out_size;
  const float* x         = (const float*)d_in[0];
  const int*   ei        = (const int*)d_in[1];
  const float* ln1_g     = (const float*)d_in[2];
  const float* ln1_b     = (const float*)d_in[3];
  const float* ln2_g     = (const float*)d_in[4];
  const float* ln2_b     = (const float*)d_in[5];
  const float* ln3_g     = (const float*)d_in[6];
  const float* ln3_b     = (const float*)d_in[7];
  const float* in_proj_w = (const float*)d_in[8];
  const float* in_proj_b = (const float*)d_in[9];
  const float* out_proj_w= (const float*)d_in[10];
  const float* out_proj_b= (const float*)d_in[11];
  const float* msg_w     = (const float*)d_in[12];
  const float* msg_b     = (const float*)d_in[13];
  const float* gru_wih   = (const float*)d_in[14];
  const float* gru_whh   = (const float*)d_in[15];
  const float* gru_bih   = (const float*)d_in[16];
  const float* gru_bhh   = (const float*)d_in[17];
  const float* ffn_w1    = (const float*)d_in[18];
  const float* ffn_b1    = (const float*)d_in[19];
  const float* ffn_w2    = (const float*)d_in[20];
  const float* ffn_b2    = (const float*)d_in[21];
  const float* gate_w    = (const float*)d_in[22];
  const float* gate_b    = (const float*)d_in[23];

  char* ws = (char*)d_ws;
  size_t o = 0;
  auto alloc = [&](size_t b) { size_t r = o; o += (b + 255) & ~(size_t)255; return r; };
  const size_t o_xn1b  = alloc((size_t)N_ * D_ * 2);
  const size_t o_xn2b  = alloc((size_t)N_ * D_ * 2);
  const size_t o_ipb   = alloc((size_t)TD_ * D_ * 2);
  const size_t o_w1b   = alloc((size_t)D_ * D_ * 2);
  const size_t o_wihb  = alloc((size_t)TD_ * D_ * 2);
  const size_t o_whhb  = alloc((size_t)TD_ * D_ * 2);  // whhb & w2b adjacent: [whh|W2]
  const size_t o_w2b   = alloc((size_t)D_ * D_ * 2);
  const size_t o_opb   = alloc((size_t)D_ * D_ * 2);
  const size_t o_f1b   = alloc((size_t)FD_ * D_ * 2);
  const size_t o_f2b   = alloc((size_t)D_ * FD_ * 2);
  const size_t o_bcat  = alloc((size_t)2048 * 4);
  const size_t o_degi  = alloc((size_t)N_ * 4);
  const size_t o_rs    = alloc((size_t)(N_ + 1) * 4);
  const size_t o_cur   = alloc((size_t)N_ * 4);
  const size_t o_ss    = alloc((size_t)E_ * 4);
  const size_t o_rsum  = alloc((size_t)H_ * N_ * 4);   // per-chunk slabs of H_*CM_
  const size_t o_rinv  = alloc((size_t)H_ * N_ * 4);
  const size_t o_aggrb = alloc((size_t)N_ * D_ * 2);
  const size_t o_gsb   = alloc((size_t)N_ * D_ * 2);
  const size_t o_xm    = alloc((size_t)N_ * D_ * 4);
  const size_t o_xn3b  = alloc((size_t)N_ * D_ * 2);
  const size_t o_big1  = alloc((size_t)H_ * CM_ * N_ * 2);  // scc P' (134 MB)
  const size_t o_big2  = alloc((size_t)N_ * FD_ * 2);       // h1b
  const size_t o_rn    = alloc((size_t)N_ * TD_ * 4);       // gi -> qkvb+vT+ctx
  const size_t o_ro    = alloc((size_t)N_ * 2048 * 4);      // ghp -> xattn+xc
  if (ws_size < o) return;

  u16* xn1b   = (u16*)(ws + o_xn1b);
  u16* xn2b   = (u16*)(ws + o_xn2b);
  u16* ipb    = (u16*)(ws + o_ipb);
  u16* w1b    = (u16*)(ws + o_w1b);
  u16* wihb   = (u16*)(ws + o_wihb);
  u16* whhb   = (u16*)(ws + o_whhb);
  u16* w2b    = (u16*)(ws + o_w2b);
  u16* opb    = (u16*)(ws + o_opb);
  u16* f1b    = (u16*)(ws + o_f1b);
  u16* f2b    = (u16*)(ws + o_f2b);
  float* bcat = (float*)(ws + o_bcat);
  int* degi   = (int*)(ws + o_degi);
  int* rs     = (int*)(ws + o_rs);
  int* cur    = (int*)(ws + o_cur);
  int* ssrc   = (int*)(ws + o_ss);
  float* rsumA= (float*)(ws + o_rsum);
  float* rinvA= (float*)(ws + o_rinv);
  u16* aggrb  = (u16*)(ws + o_aggrb);
  u16* gsb    = (u16*)(ws + o_gsb);
  float* xm   = (float*)(ws + o_xm);
  u16* xn3b   = (u16*)(ws + o_xn3b);
  u16* scc    = (u16*)(ws + o_big1);
  u16* h1b    = (u16*)(ws + o_big2);
  float* gi   = (float*)(ws + o_rn);
  u16* qkvb   = (u16*)(ws + o_rn);
  u16* vT     = (u16*)(ws + o_rn + (size_t)N_ * TD_ * 2);
  float* ctx  = (float*)(ws + o_rn + (size_t)N_ * TD_ * 2 + (size_t)D_ * N_ * 2);
  float* ghp  = (float*)(ws + o_ro);
  float* xattn= (float*)(ws + o_ro);
  float* xc   = (float*)(ws + o_ro + (size_t)N_ * D_ * 4);

  float* outp = (float*)d_out;
  float* attn = (float*)d_out + (size_t)N_ * D_;

  hipMemsetAsync(degi, 0, (size_t)N_ * 4, stream);
  hipMemsetAsync(rsumA, 0, (size_t)H_ * N_ * 4, stream);

  conv_weights<<<5122, 256, 0, stream>>>(in_proj_w, gru_wih, gru_whh, out_proj_w,
                                         ffn_w1, ffn_w2, msg_w, gru_bhh,
                                         ipb, wihb, whhb, opb, f1b, f2b, w1b, w2b, bcat);

  ln12_kernel<<<N_, 128, 0, stream>>>(x, ln1_g, ln1_b, ln2_g, ln2_b, xn1b, xn2b);

  // CSR build + sparse gather-sum
  hist_kernel<<<512, 256, 0, stream>>>(ei, degi);
  scan_kernel<<<1, 1024, 0, stream>>>(degi, rs, cur);
  scatter_kernel<<<512, 256, 0, stream>>>(ei, cur, ssrc);
  gather_kernel<<<N_, 128, 0, stream>>>(rs, ssrc, xn1b, gsb);

  // ghp = xn1 @ [whh | W2]^T + [bhh | 0]
  gemm_bt<128, 128, 64, 2, 2, 4, 4, 0, true, 0, 0><<<dim3(32, 16), 256, 0, stream>>>(
      xn1b, D_, whhb, D_, ghp, 2048, bcat, 1.0f, D_, 0, 0, 0, nullptr, nullptr, nullptr);
  // aggr = finalize(gather_sum @ W1^T)  (MODE 7, fused)
  gemm_bt<64, 64, 64, 2, 2, 2, 2, 7, false, 0, 0><<<dim3(64, 8), 256, 0, stream>>>(
      gsb, D_, w1b, D_, aggrb, D_, nullptr, 1.0f, D_, 0, 0, 0, ghp, msg_b, degi);

  // GRU input gates + update
  gemm_bt<128, 128, 64, 2, 2, 4, 4, 0, true, 0, 0><<<dim3(32, 12), 256, 0, stream>>>(
      aggrb, D_, wihb, D_, gi, TD_, gru_bih, 1.0f, D_, 0, 0, 0, nullptr, nullptr, nullptr);
  gru_kernel<<<8192, 256, 0, stream>>>(gi, ghp, xn1b, xm);

  // qkv projection (gi region now dead)
  gemm_bt<128, 128, 64, 2, 2, 4, 4, 1, true, 0, 0><<<dim3(32, 12), 256, 0, stream>>>(
      xn2b, D_, ipb, D_, qkvb, TD_, in_proj_b, 1.0f, D_, 0, 0, 0, nullptr, nullptr, nullptr);
  transpose_bf16<<<dim3(16, 128), dim3(32, 32), 0, stream>>>(qkvb + 1024, TD_, vT, N_);
  hipMemsetAsync(ctx, 0, (size_t)N_ * D_ * 4, stream);

  // attention: scores+exp+rowsum -> streaming mean (+rinv) -> DMA PV (2 chunks)
  for (int c = 0; c < N_ / CM_; ++c) {
    float* rsumC = rsumA + (size_t)c * H_ * CM_;
    float* rinvC = rinvA + (size_t)c * H_ * CM_;
    gemm_bt<128, 128, 64, 2, 2, 4, 4, 5, false, 1, 0><<<dim3(CM_ / 128, 32, 8), 256, 0, stream>>>(
        qkvb + (size_t)c * CM_ * TD_, TD_, qkvb + 512, TD_, scc, N_, nullptr,
        0.125f, 64, 64, 64, (size_t)CM_ * N_, rsumC, nullptr, nullptr);
    mean_kernel<<<CM_, 256, 0, stream>>>(scc, rsumC, rinvC, attn + (size_t)c * CM_ * N_);
    gemm_bt<64, 64, 64, 2, 2, 2, 2, 6, false, 2, 0><<<dim3(CM_ / 64, 8, 4), 256, 0, stream>>>(
        scc, N_, vT, N_, ctx + (size_t)c * CM_ * D_, D_, nullptr, 1.0f, 1024,
        (size_t)CM_ * N_, (size_t)64 * N_, 64, nullptr, rinvC, nullptr);
  }

  // out_proj (ctx f32 cast-staged)
  gemm_bt<64, 64, 64, 2, 2, 2, 2, 0, true, 0, 2><<<dim3(64, 8), 256, 0, stream>>>(
      (const u16*)ctx, D_, opb, D_, xattn, D_, out_proj_b, 1.0f, D_, 0, 0, 0,
      nullptr, nullptr, nullptr);

  combine_ln3<<<N_, 128, 0, stream>>>(x, xm, xattn, gate_w, gate_b, ln3_g, ln3_b, xc, xn3b);

  // FFN: GELU fused; residual fused in FFN2 epilogue
  gemm_bt<128, 128, 64, 2, 2, 4, 4, 3, true, 0, 0><<<dim3(32, 16), 256, 0, stream>>>(
      xn3b, D_, f1b, D_, h1b, FD_, ffn_b1, 1.0f, D_, 0, 0, 0, nullptr, nullptr, nullptr);
  gemm_bt<64, 64, 64, 2, 2, 2, 2, 4, true, 0, 0><<<dim3(64, 8), 256, 0, stream>>>(
      h1b, FD_, f2b, FD_, outp, D_, ffn_b2, 1.0f, FD_, 0, 0, 0, xc, nullptr, nullptr);
}